// Round 1
// baseline (184.040 us; speedup 1.0000x reference)
//
#include <hip/hip_runtime.h>

#define NB 16
#define BATCHES 4

// Workspace layout
struct WS {
    unsigned int mm[16];                         // per batch: fminEnc, fmaxEnc, mminEnc, mmaxEnc
    unsigned long long joint[BATCHES * 256];     // fixed-point (x 2^32) joint histogram [b][f][m]
    unsigned int fcount[BATCHES * NB];           // exact integer fixed-bin counts
};

// order-preserving float<->uint encoding (works for all floats incl. negatives)
__device__ __forceinline__ unsigned int fenc(float x) {
    unsigned int u = __float_as_uint(x);
    return (u & 0x80000000u) ? ~u : (u | 0x80000000u);
}
__device__ __forceinline__ float fdec(unsigned int u) {
    unsigned int v = (u & 0x80000000u) ? (u ^ 0x80000000u) : ~u;
    return __uint_as_float(v);
}

__global__ __launch_bounds__(256) void k_init(WS* ws) {
    int t = threadIdx.x;
    if (t < 16) ws->mm[t] = (t & 1) ? 0u : 0xFFFFFFFFu;  // even slots = mins, odd = maxes
    for (int i = t; i < BATCHES * 256; i += 256) ws->joint[i] = 0ull;
    for (int i = t; i < BATCHES * NB; i += 256) ws->fcount[i] = 0u;
}

__global__ __launch_bounds__(256) void k_minmax(const float4* __restrict__ mov,
                                                const float4* __restrict__ fix,
                                                WS* __restrict__ ws, int nvec) {
    int b = blockIdx.y;
    const float4* m4 = mov + (size_t)b * nvec;
    const float4* f4 = fix + (size_t)b * nvec;
    int stride = gridDim.x * blockDim.x;
    float fmn = 3.4e38f, fmx = -3.4e38f, mmn = 3.4e38f, mmx = -3.4e38f;
    for (int i = blockIdx.x * blockDim.x + threadIdx.x; i < nvec; i += stride) {
        float4 f = f4[i];
        float4 m = m4[i];
        fmn = fminf(fmn, fminf(fminf(f.x, f.y), fminf(f.z, f.w)));
        fmx = fmaxf(fmx, fmaxf(fmaxf(f.x, f.y), fmaxf(f.z, f.w)));
        mmn = fminf(mmn, fminf(fminf(m.x, m.y), fminf(m.z, m.w)));
        mmx = fmaxf(mmx, fmaxf(fmaxf(m.x, m.y), fmaxf(m.z, m.w)));
    }
    __shared__ float4 red[256];
    int t = threadIdx.x;
    red[t] = make_float4(fmn, fmx, mmn, mmx);
    __syncthreads();
    for (int s = 128; s > 0; s >>= 1) {
        if (t < s) {
            float4 a = red[t], c = red[t + s];
            red[t] = make_float4(fminf(a.x, c.x), fmaxf(a.y, c.y),
                                 fminf(a.z, c.z), fmaxf(a.w, c.w));
        }
        __syncthreads();
    }
    if (t == 0) {
        float4 r = red[0];
        atomicMin(&ws->mm[b * 4 + 0], fenc(r.x));
        atomicMax(&ws->mm[b * 4 + 1], fenc(r.y));
        atomicMin(&ws->mm[b * 4 + 2], fenc(r.z));
        atomicMax(&ws->mm[b * 4 + 3], fenc(r.w));
    }
}

__global__ __launch_bounds__(256) void k_hist(const float4* __restrict__ mov,
                                              const float4* __restrict__ fix,
                                              WS* __restrict__ ws, int nvec) {
    __shared__ unsigned long long ldsJ[2][256];
    __shared__ unsigned int ldsF[NB];
    int t = threadIdx.x;
    int b = blockIdx.y;

    for (int i = t; i < 512; i += 256) ((unsigned long long*)ldsJ)[i] = 0ull;
    if (t < NB) ldsF[t] = 0u;

    float fmin_ = fdec(ws->mm[b * 4 + 0]);
    float fmax_ = fdec(ws->mm[b * 4 + 1]);
    float mmin_ = fdec(ws->mm[b * 4 + 2]);
    float mmax_ = fdec(ws->mm[b * 4 + 3]);
    float fbs = (fmax_ - fmin_) / 12.0f;   // nb - 2*PADDING
    float mbs = (mmax_ - mmin_) / 12.0f;
    float fsh = fmin_ / fbs - 2.0f;        // PADDING
    float msh = mmin_ / mbs - 2.0f;
    __syncthreads();

    int copy = (t >> 6) & 1;
    const float4* m4 = mov + (size_t)b * nvec;
    const float4* f4 = fix + (size_t)b * nvec;
    int stride = gridDim.x * blockDim.x;

    auto proc = [&](float fv, float mv) {
        float fterm = fv / fbs - fsh;
        int fi = (int)fterm;               // fterm >= ~2, trunc == floor
        fi = fi < 2 ? 2 : (fi > NB - 3 ? NB - 3 : fi);
        float mterm = mv / mbs - msh;
        int mi_ = (int)mterm;
        mi_ = mi_ < 2 ? 2 : (mi_ > NB - 3 ? NB - 3 : mi_);
        atomicAdd(&ldsF[fi], 1u);
        float b0 = (float)(mi_ - 1) - mterm;   // u for off = -1
        int baseIdx = fi * NB + mi_ - 1;
#pragma unroll
        for (int k = 0; k < 4; k++) {
            float u = b0 + (float)k;
            float au = fabsf(u);
            float su = au * au;
            float w;
            if (au < 1.0f)
                w = (4.0f - 6.0f * su + 3.0f * su * au) * (1.0f / 6.0f);
            else if (au < 2.0f)
                w = (8.0f - 12.0f * au + 6.0f * su - su * au) * (1.0f / 6.0f);
            else
                w = 0.0f;
            w = fmaxf(w, 0.0f);
            unsigned long long q = (unsigned long long)((double)w * 4294967296.0);
            atomicAdd(&ldsJ[copy][baseIdx + k], q);
        }
    };

    for (int i = blockIdx.x * blockDim.x + t; i < nvec; i += stride) {
        float4 fv = f4[i];
        float4 mv = m4[i];
        proc(fv.x, mv.x);
        proc(fv.y, mv.y);
        proc(fv.z, mv.z);
        proc(fv.w, mv.w);
    }
    __syncthreads();

    unsigned long long v = ldsJ[0][t] + ldsJ[1][t];
    if (v) atomicAdd(&ws->joint[b * 256 + t], v);
    if (t < NB) {
        unsigned int c = ldsF[t];
        if (c) atomicAdd(&ws->fcount[b * NB + t], c);
    }
}

__global__ __launch_bounds__(256) void k_final(const WS* __restrict__ ws,
                                               float* __restrict__ out, double invN) {
    __shared__ double shp[256];
    __shared__ double shr[256];
    int t = threadIdx.x;
    double acc = 0.0;
    for (int b = 0; b < BATCHES; b++) {
        double jt = (double)ws->joint[b * 256 + t];
        shr[t] = jt;
        __syncthreads();
        for (int s = 128; s > 0; s >>= 1) {
            if (t < s) shr[t] += shr[t + s];
            __syncthreads();
        }
        double total = shr[0];
        __syncthreads();
        double p = jt / total;
        shp[t] = p;
        __syncthreads();
        double val = (p > 0.0) ? p * log(p) : 0.0;
        if (t < NB) {
            double mp = 0.0;
            for (int f = 0; f < NB; f++) mp += shp[f * NB + t];
            if (mp > 0.0) val -= mp * log(mp);
            double fp = (double)ws->fcount[b * NB + t] * invN;
            if (fp > 0.0) val -= fp * log(fp);
        }
        __syncthreads();  // done reading shp/shr
        shr[t] = val;
        __syncthreads();
        for (int s = 128; s > 0; s >>= 1) {
            if (t < s) shr[t] += shr[t + s];
            __syncthreads();
        }
        if (t == 0) acc += shr[0];
        __syncthreads();
    }
    if (t == 0) out[0] = (float)(-acc / (double)BATCHES);
}

extern "C" void kernel_launch(void* const* d_in, const int* in_sizes, int n_in,
                              void* d_out, int out_size, void* d_ws, size_t ws_size,
                              hipStream_t stream) {
    const float* mov = (const float*)d_in[0];
    const float* fix = (const float*)d_in[1];
    float* out = (float*)d_out;
    WS* ws = (WS*)d_ws;

    int total = in_sizes[0];
    int N = total / BATCHES;      // 128^3 = 2097152
    int nvec = N / 4;

    k_init<<<1, 256, 0, stream>>>(ws);

    dim3 grid(256, BATCHES);
    k_minmax<<<grid, 256, 0, stream>>>((const float4*)mov, (const float4*)fix, ws, nvec);
    k_hist<<<grid, 256, 0, stream>>>((const float4*)mov, (const float4*)fix, ws, nvec);
    k_final<<<1, 256, 0, stream>>>(ws, out, 1.0 / (double)N);
}